// Round 15
// baseline (236.679 us; speedup 1.0000x reference)
//
#include <hip/hip_runtime.h>

#define NG 16
#define NC 4
#define BPB 8      // batch items per block (2 quads per thread)
#define TSTEPS 8

__device__ __forceinline__ void fma4(float w, const float4& s, float4& a) {
    a.x = fmaf(w, s.x, a.x);
    a.y = fmaf(w, s.y, a.y);
    a.z = fmaf(w, s.z, a.z);
    a.w = fmaf(w, s.w, a.w);
}

__device__ __forceinline__ float4 lrelu4(float4 v) {
    float4 r;
    r.x = fmaxf(v.x, 0.1f * v.x);
    r.y = fmaxf(v.y, 0.1f * v.y);
    r.z = fmaxf(v.z, 0.1f * v.z);
    r.w = fmaxf(v.w, 0.1f * v.w);
    return r;
}

// DPP row shift within 16-lane rows; bound_ctrl=1 zero-fills at row edges
// (matches reference zero padding; OOB weights pre-zeroed anyway).
// 0x111/0x112 = row_shr:1/2 (tap x-1/x-2); 0x101/0x102 = row_shl:1/2 (x+1/x+2).
template<int CTRL>
__device__ __forceinline__ float dppf(float x) {
    return __int_as_float(__builtin_amdgcn_update_dpp(
        0, __float_as_int(x), CTRL, 0xF, 0xF, true));
}
template<int CTRL>
__device__ __forceinline__ float4 dpp4(float4 v) {
    float4 r;
    r.x = dppf<CTRL>(v.x);
    r.y = dppf<CTRL>(v.y);
    r.z = dppf<CTRL>(v.z);
    r.w = dppf<CTRL>(v.w);
    return r;
}

// Wt[(c*25+u*5+v)*256 + pix] : float4 over o, OOB (u,v) pre-zeroed.
// Original W: [y][x][o][c][u][v] (flat: pix*400 + o*100 + c*25 + u*5 + v)
__global__ void wt_transpose(const float* __restrict__ W, float4* __restrict__ Wt) {
    int t = blockIdx.x * 256 + threadIdx.x;   // 0..25599
    if (t >= 25600) return;
    int r = t >> 8;            // c*25 + u*5 + v
    int pix = t & 255;
    int c = r / 25, uv = r - c * 25, u = uv / 5, v = uv - u * 5;
    int y = pix >> 4, x = pix & 15;
    float4 w = make_float4(0.f, 0.f, 0.f, 0.f);
    if ((unsigned)(y + u - 2) < 16u && (unsigned)(x + v - 2) < 16u) {
        int base = pix * 400 + c * 25 + uv;
        w.x = W[base];
        w.y = W[base + 100];
        w.z = W[base + 200];
        w.w = W[base + 300];
    }
    Wt[r * 256 + pix] = w;
}

// R14's compute structure (256 threads = pixels, BPB=8, tap-major reload,
// DPP x-taps, ~83 live VGPR) with SINGLE-buffered 32 KiB state LDS:
// 5 blocks/CU = 20 waves/CU = 5 waves/SIMD (2.5x R14's TLP) -- barrier
// drains and weight-load latency now interleave across 5 resident blocks
// instead of idling the VALU at 2 waves/SIMD (the R14 lesson: clean
// registers alone didn't help; stall coverage is the limiter).
// Cost: 2 barriers/step (read-drain + write-visible). launch_bounds(256,5)
// -> VGPR budget 512/5 ~= 102 >= 83 live.
// LDS layout: f4 idx = ((c*16+y)*16+x)*2 + (q ^ ((x>>2)&1)) -- each 16-lane
// row covers all 8 b128 bank-groups (conflict-minimal, R14-proven).
__global__ __launch_bounds__(256, 5)
void reservoir_kernel(const float* __restrict__ X, const float4* __restrict__ Wt,
                      float* __restrict__ out, int batch) {
    __shared__ float4 smv[NC * NG * NG * 2];   // 32768 B
    float* smf = reinterpret_cast<float*>(smv);

    const int tid = threadIdx.x;        // pixel index
    const int y = tid >> 4;
    const int x = tid & 15;
    const long itemBase = (long)blockIdx.x * BPB;

    const int swx = (x >> 2) & 1;
    const int q0 = swx;          // phys slot of quad 0 (items 0-3)
    const int q1 = swx ^ 1;      // phys slot of quad 1 (items 4-7)

    // ---- init: X (first 784 of 1024 slots) -> LDS ----
    for (int b = 0; b < BPB; ++b) {
        long item = itemBase + b;
        #pragma unroll
        for (int k = 0; k < 4; ++k) {
            int idx = tid + k * 256;
            float v = 0.f;
            if (idx < 784 && item < batch)
                v = __builtin_nontemporal_load(&X[item * 784 + idx]);
            int c = idx >> 8, rem = idx & 255, yy = rem >> 4, xx = rem & 15;
            int phys = (b >> 2) ^ ((xx >> 2) & 1);
            smf[((((c * NG + yy) * NG + xx) << 1) + phys) * 4 + (b & 3)] = v;
        }
    }

    // ---- weights: single-buffered 5 x float4, chunk 0 preloaded ----
    const float4* Wp = Wt + tid;
    float4 w0 = Wp[0], w1 = Wp[256], w2 = Wp[512], w3 = Wp[768], w4 = Wp[1024];
    int wnext = 1280;    // f4 offset of next chunk (chunk k at k*1280)

    __syncthreads();

    // one tap across both quads: 32 v_fma
#define TAP(WV, T0, T1) \
    fma4(WV.x, T0, a00); fma4(WV.x, T1, a01); \
    fma4(WV.y, T0, a10); fma4(WV.y, T1, a11); \
    fma4(WV.z, T0, a20); fma4(WV.z, T1, a21); \
    fma4(WV.w, T0, a30); fma4(WV.w, T1, a31);

    #pragma unroll 1
    for (int t = 0; t < TSTEPS; ++t) {
        float4 a00 = {0,0,0,0}, a01 = {0,0,0,0};
        float4 a10 = {0,0,0,0}, a11 = {0,0,0,0};
        float4 a20 = {0,0,0,0}, a21 = {0,0,0,0};
        float4 a30 = {0,0,0,0}, a31 = {0,0,0,0};

        #pragma unroll 1
        for (int c = 0; c < NC; ++c) {
            #pragma unroll 1
            for (int u = 0; u < 5; ++u) {
                int yy = y + u - 2;
                yy = yy < 0 ? 0 : (yy > 15 ? 15 : yy);   // OOB rows: w pre-zeroed
                const int rb = ((c * NG + yy) * NG + x) << 1;
                const float4 s0 = smv[rb + q0];
                const float4 s1 = smv[rb + q1];

                // tap-major: consume w_v on both quads, then reload w_v
                TAP(w2, s0, s1)
                w2 = Wp[wnext + 512];
                { const float4 t0 = dpp4<0x111>(s0), t1 = dpp4<0x111>(s1);  // x-1
                  TAP(w1, t0, t1) }
                w1 = Wp[wnext + 256];
                { const float4 t0 = dpp4<0x101>(s0), t1 = dpp4<0x101>(s1);  // x+1
                  TAP(w3, t0, t1) }
                w3 = Wp[wnext + 768];
                { const float4 t0 = dpp4<0x112>(s0), t1 = dpp4<0x112>(s1);  // x-2
                  TAP(w0, t0, t1) }
                w0 = Wp[wnext];
                { const float4 t0 = dpp4<0x102>(s0), t1 = dpp4<0x102>(s1);  // x+2
                  TAP(w4, t0, t1) }
                w4 = Wp[wnext + 1024];

                wnext += 1280;
                if (wnext >= 25600) wnext = 0;   // chunk 19 -> chunk 0
            }
        }

        a00 = lrelu4(a00); a01 = lrelu4(a01);
        a10 = lrelu4(a10); a11 = lrelu4(a11);
        a20 = lrelu4(a20); a21 = lrelu4(a21);
        a30 = lrelu4(a30); a31 = lrelu4(a31);

        if (t < TSTEPS - 1) {
            __syncthreads();   // all reads of S[t] complete before overwrite
            const int pb = ((y * NG) + x) << 1;   // c=0 row
            smv[pb + 0 * 512 + q0] = a00;  smv[pb + 0 * 512 + q1] = a01;
            smv[pb + 1 * 512 + q0] = a10;  smv[pb + 1 * 512 + q1] = a11;
            smv[pb + 2 * 512 + q0] = a20;  smv[pb + 2 * 512 + q1] = a21;
            smv[pb + 3 * 512 + q0] = a30;  smv[pb + 3 * 512 + q1] = a31;
            __syncthreads();   // writes visible before next read phase
        } else {
            // channel-mean: p0 = items 0-3, p1 = items 4-7
            float4 p0, p1;
            p0.x = (a00.x + a10.x + a20.x + a30.x) * 0.25f;
            p0.y = (a00.y + a10.y + a20.y + a30.y) * 0.25f;
            p0.z = (a00.z + a10.z + a20.z + a30.z) * 0.25f;
            p0.w = (a00.w + a10.w + a20.w + a30.w) * 0.25f;
            p1.x = (a01.x + a11.x + a21.x + a31.x) * 0.25f;
            p1.y = (a01.y + a11.y + a21.y + a31.y) * 0.25f;
            p1.z = (a01.z + a11.z + a21.z + a31.z) * 0.25f;
            p1.w = (a01.w + a11.w + a21.w + a31.w) * 0.25f;
            const long ob = itemBase * 256 + tid;
            if (itemBase + 0 < batch) __builtin_nontemporal_store(p0.x, &out[ob + 0 * 256]);
            if (itemBase + 1 < batch) __builtin_nontemporal_store(p0.y, &out[ob + 1 * 256]);
            if (itemBase + 2 < batch) __builtin_nontemporal_store(p0.z, &out[ob + 2 * 256]);
            if (itemBase + 3 < batch) __builtin_nontemporal_store(p0.w, &out[ob + 3 * 256]);
            if (itemBase + 4 < batch) __builtin_nontemporal_store(p1.x, &out[ob + 4 * 256]);
            if (itemBase + 5 < batch) __builtin_nontemporal_store(p1.y, &out[ob + 5 * 256]);
            if (itemBase + 6 < batch) __builtin_nontemporal_store(p1.z, &out[ob + 6 * 256]);
            if (itemBase + 7 < batch) __builtin_nontemporal_store(p1.w, &out[ob + 7 * 256]);
        }
    }
}

extern "C" void kernel_launch(void* const* d_in, const int* in_sizes, int n_in,
                              void* d_out, int out_size, void* d_ws, size_t ws_size,
                              hipStream_t stream) {
    const float* X = (const float*)d_in[0];
    const float* W = (const float*)d_in[1];
    float* out = (float*)d_out;
    const int batch = in_sizes[0] / 784;            // 8192
    const int blocks = (batch + BPB - 1) / BPB;     // 1024

    wt_transpose<<<100, 256, 0, stream>>>(W, (float4*)d_ws);
    reservoir_kernel<<<blocks, 256, 0, stream>>>(
        X, (const float4*)d_ws, out, batch);
}

// Round 16
// 214.131 us; speedup vs baseline: 1.1053x; 1.1053x over previous
//
#include <hip/hip_runtime.h>

#define NG 16
#define NC 4
#define BPB 16     // batch items per block (= per thread)
#define TSTEPS 8
#define PITCH 64   // float4 per (c,y) row: 16 x * 4 quad-slots (swizzled)
#define CROW (NG * PITCH)   // 1024 float4 per channel

__device__ __forceinline__ void fma4(float w, const float4& s, float4& a) {
    a.x = fmaf(w, s.x, a.x);
    a.y = fmaf(w, s.y, a.y);
    a.z = fmaf(w, s.z, a.z);
    a.w = fmaf(w, s.w, a.w);
}

__device__ __forceinline__ float4 lrelu4(float4 v) {
    float4 r;
    r.x = fmaxf(v.x, 0.1f * v.x);
    r.y = fmaxf(v.y, 0.1f * v.y);
    r.z = fmaxf(v.z, 0.1f * v.z);
    r.w = fmaxf(v.w, 0.1f * v.w);
    return r;
}

// DPP row shift within 16-lane rows; bound_ctrl=1 zero-fills at row edges
// (matches reference zero padding; OOB weights pre-zeroed anyway).
// 0x111/0x112 = row_shr:1/2 (tap x-1/x-2); 0x101/0x102 = row_shl:1/2 (x+1/x+2).
template<int CTRL>
__device__ __forceinline__ float dppf(float x) {
    return __int_as_float(__builtin_amdgcn_update_dpp(
        0, __float_as_int(x), CTRL, 0xF, 0xF, true));
}
template<int CTRL>
__device__ __forceinline__ float4 dpp4(float4 v) {
    float4 r;
    r.x = dppf<CTRL>(v.x);
    r.y = dppf<CTRL>(v.y);
    r.z = dppf<CTRL>(v.z);
    r.w = dppf<CTRL>(v.w);
    return r;
}

// Wt[(c*25+u*5+v)*256 + pix] : float4 over o, OOB (u,v) pre-zeroed.
// Original W: [y][x][o][c][u][v] (flat: pix*400 + o*100 + c*25 + u*5 + v)
__global__ void wt_transpose(const float* __restrict__ W, float4* __restrict__ Wt) {
    int t = blockIdx.x * 256 + threadIdx.x;   // 0..25599
    if (t >= 25600) return;
    int r = t >> 8;            // c*25 + u*5 + v
    int pix = t & 255;
    int c = r / 25, uv = r - c * 25, u = uv / 5, v = uv - u * 5;
    int y = pix >> 4, x = pix & 15;
    float4 w = make_float4(0.f, 0.f, 0.f, 0.f);
    if ((unsigned)(y + u - 2) < 16u && (unsigned)(x + v - 2) < 16u) {
        int base = pix * 400 + c * 25 + uv;
        w.x = W[base];
        w.y = W[base + 100];
        w.z = W[base + 200];
        w.w = W[base + 300];
    }
    Wt[r * 256 + pix] = w;
}

// R11 (the issue-optimal 214 us kernel: 256 threads = pixels, BPB=16, 64 KiB
// LDS, issue = 157 us ~= the arithmetic floor at the chip's measured dense-
// VALU clock) with ONE change: TAP-MAJOR weight reload. R11 reloaded all 5
// w_v at chunk end, first use a few instructions later -> ~200 cyc L2 latency
// exposed per chunk at 2 waves/SIMD (its 27% stall). Here: consume tap v
// across all 4 quads (64 FMA), then reload w_v -- next use is ~4/5 chunk
// (~500-700 cyc) away, hidden by anti-dependency construction (R12-proven
// mechanism). No other change: launch_bounds(256,2) granted 92 VGPRs in
// R11/R14 (256-thread blocks are the only shape the allocator treats sanely).
__global__ __launch_bounds__(256, 2)
void reservoir_kernel(const float* __restrict__ X, const float4* __restrict__ Wt,
                      float* __restrict__ out, int batch) {
    __shared__ float4 smv[NC * CROW];   // 65536 B
    float* smf = reinterpret_cast<float*>(smv);

    const int tid = threadIdx.x;        // pixel index
    const int y = tid >> 4;
    const int x = tid & 15;
    const long itemBase = (long)blockIdx.x * BPB;

    const int sw = (x >> 1) & 3;        // quad-slot swizzle
    const int xb = x << 2;

    // ---- init: X (first 784 of 1024 slots) -> LDS ----
    for (int b = 0; b < BPB; ++b) {
        long item = itemBase + b;
        #pragma unroll
        for (int k = 0; k < 4; ++k) {
            int idx = tid + k * 256;
            float v = 0.f;
            if (idx < 784 && item < batch)
                v = __builtin_nontemporal_load(&X[item * 784 + idx]);
            int c = idx >> 8, rem = idx & 255, yy = rem >> 4, xx = rem & 15;
            int phys = (b >> 2) ^ ((xx >> 1) & 3);
            smf[(((c * NG + yy) << 6) + (xx << 2) + phys) * 4 + (b & 3)] = v;
        }
    }

    // ---- weights: single-buffered 5 x float4, chunk 0 preloaded ----
    const float4* Wp = Wt + tid;
    float4 w0 = Wp[0], w1 = Wp[256], w2 = Wp[512], w3 = Wp[768], w4 = Wp[1024];
    int wnext = 1280;    // f4 offset of next chunk (chunk k at k*1280)

    __syncthreads();

    // one tap (one weight f4) across all 4 quads: 64 v_fma
#define TAP16(WV, T0, T1, T2, T3) \
    fma4(WV.x, T0, a00); fma4(WV.x, T1, a01); fma4(WV.x, T2, a02); fma4(WV.x, T3, a03); \
    fma4(WV.y, T0, a10); fma4(WV.y, T1, a11); fma4(WV.y, T2, a12); fma4(WV.y, T3, a13); \
    fma4(WV.z, T0, a20); fma4(WV.z, T1, a21); fma4(WV.z, T2, a22); fma4(WV.z, T3, a23); \
    fma4(WV.w, T0, a30); fma4(WV.w, T1, a31); fma4(WV.w, T2, a32); fma4(WV.w, T3, a33);

    #pragma unroll 1
    for (int t = 0; t < TSTEPS; ++t) {
        float4 a00 = {0,0,0,0}, a01 = {0,0,0,0}, a02 = {0,0,0,0}, a03 = {0,0,0,0};
        float4 a10 = {0,0,0,0}, a11 = {0,0,0,0}, a12 = {0,0,0,0}, a13 = {0,0,0,0};
        float4 a20 = {0,0,0,0}, a21 = {0,0,0,0}, a22 = {0,0,0,0}, a23 = {0,0,0,0};
        float4 a30 = {0,0,0,0}, a31 = {0,0,0,0}, a32 = {0,0,0,0}, a33 = {0,0,0,0};

        #pragma unroll 1
        for (int c = 0; c < NC; ++c) {
            #pragma unroll 1
            for (int u = 0; u < 5; ++u) {
                int yy = y + u - 2;
                yy = yy < 0 ? 0 : (yy > 15 ? 15 : yy);   // OOB rows: w pre-zeroed
                const int rb = ((c * NG + yy) << 6) + xb;
                const float4 s0 = smv[rb + (0 ^ sw)];
                const float4 s1 = smv[rb + (1 ^ sw)];
                const float4 s2 = smv[rb + (2 ^ sw)];
                const float4 s3 = smv[rb + (3 ^ sw)];

                // tap-major: consume w_v on all quads, then reload w_v; its
                // next use is ~4/5 chunk away -> L2 latency hidden.
                TAP16(w2, s0, s1, s2, s3)
                w2 = Wp[wnext + 512];
                { const float4 t0 = dpp4<0x111>(s0), t1 = dpp4<0x111>(s1),
                               t2 = dpp4<0x111>(s2), t3 = dpp4<0x111>(s3);  // x-1
                  TAP16(w1, t0, t1, t2, t3) }
                w1 = Wp[wnext + 256];
                { const float4 t0 = dpp4<0x101>(s0), t1 = dpp4<0x101>(s1),
                               t2 = dpp4<0x101>(s2), t3 = dpp4<0x101>(s3);  // x+1
                  TAP16(w3, t0, t1, t2, t3) }
                w3 = Wp[wnext + 768];
                { const float4 t0 = dpp4<0x112>(s0), t1 = dpp4<0x112>(s1),
                               t2 = dpp4<0x112>(s2), t3 = dpp4<0x112>(s3);  // x-2
                  TAP16(w0, t0, t1, t2, t3) }
                w0 = Wp[wnext];
                { const float4 t0 = dpp4<0x102>(s0), t1 = dpp4<0x102>(s1),
                               t2 = dpp4<0x102>(s2), t3 = dpp4<0x102>(s3);  // x+2
                  TAP16(w4, t0, t1, t2, t3) }
                w4 = Wp[wnext + 1024];

                wnext += 1280;
                if (wnext >= 25600) wnext = 0;   // chunk 19 -> chunk 0
            }
        }

        a00 = lrelu4(a00); a01 = lrelu4(a01); a02 = lrelu4(a02); a03 = lrelu4(a03);
        a10 = lrelu4(a10); a11 = lrelu4(a11); a12 = lrelu4(a12); a13 = lrelu4(a13);
        a20 = lrelu4(a20); a21 = lrelu4(a21); a22 = lrelu4(a22); a23 = lrelu4(a23);
        a30 = lrelu4(a30); a31 = lrelu4(a31); a32 = lrelu4(a32); a33 = lrelu4(a33);

        if (t < TSTEPS - 1) {
            __syncthreads();   // all reads of S[t] complete before overwrite
            const int pb = (y << 6) + xb;
            smv[0 * CROW + pb + (0 ^ sw)] = a00;
            smv[0 * CROW + pb + (1 ^ sw)] = a01;
            smv[0 * CROW + pb + (2 ^ sw)] = a02;
            smv[0 * CROW + pb + (3 ^ sw)] = a03;
            smv[1 * CROW + pb + (0 ^ sw)] = a10;
            smv[1 * CROW + pb + (1 ^ sw)] = a11;
            smv[1 * CROW + pb + (2 ^ sw)] = a12;
            smv[1 * CROW + pb + (3 ^ sw)] = a13;
            smv[2 * CROW + pb + (0 ^ sw)] = a20;
            smv[2 * CROW + pb + (1 ^ sw)] = a21;
            smv[2 * CROW + pb + (2 ^ sw)] = a22;
            smv[2 * CROW + pb + (3 ^ sw)] = a23;
            smv[3 * CROW + pb + (0 ^ sw)] = a30;
            smv[3 * CROW + pb + (1 ^ sw)] = a31;
            smv[3 * CROW + pb + (2 ^ sw)] = a32;
            smv[3 * CROW + pb + (3 ^ sw)] = a33;
            __syncthreads();   // writes visible before next read phase
        } else {
            // channel-mean: p[q] covers items 4q..4q+3
            float4 p0, p1, p2, p3;
            p0.x = (a00.x + a10.x + a20.x + a30.x) * 0.25f;
            p0.y = (a00.y + a10.y + a20.y + a30.y) * 0.25f;
            p0.z = (a00.z + a10.z + a20.z + a30.z) * 0.25f;
            p0.w = (a00.w + a10.w + a20.w + a30.w) * 0.25f;
            p1.x = (a01.x + a11.x + a21.x + a31.x) * 0.25f;
            p1.y = (a01.y + a11.y + a21.y + a31.y) * 0.25f;
            p1.z = (a01.z + a11.z + a21.z + a31.z) * 0.25f;
            p1.w = (a01.w + a11.w + a21.w + a31.w) * 0.25f;
            p2.x = (a02.x + a12.x + a22.x + a32.x) * 0.25f;
            p2.y = (a02.y + a12.y + a22.y + a32.y) * 0.25f;
            p2.z = (a02.z + a12.z + a22.z + a32.z) * 0.25f;
            p2.w = (a02.w + a12.w + a22.w + a32.w) * 0.25f;
            p3.x = (a03.x + a13.x + a23.x + a33.x) * 0.25f;
            p3.y = (a03.y + a13.y + a23.y + a33.y) * 0.25f;
            p3.z = (a03.z + a13.z + a23.z + a33.z) * 0.25f;
            p3.w = (a03.w + a13.w + a23.w + a33.w) * 0.25f;
            const long ob = itemBase * 256 + tid;
            if (itemBase + 0  < batch) __builtin_nontemporal_store(p0.x, &out[ob + 0  * 256]);
            if (itemBase + 1  < batch) __builtin_nontemporal_store(p0.y, &out[ob + 1  * 256]);
            if (itemBase + 2  < batch) __builtin_nontemporal_store(p0.z, &out[ob + 2  * 256]);
            if (itemBase + 3  < batch) __builtin_nontemporal_store(p0.w, &out[ob + 3  * 256]);
            if (itemBase + 4  < batch) __builtin_nontemporal_store(p1.x, &out[ob + 4  * 256]);
            if (itemBase + 5  < batch) __builtin_nontemporal_store(p1.y, &out[ob + 5  * 256]);
            if (itemBase + 6  < batch) __builtin_nontemporal_store(p1.z, &out[ob + 6  * 256]);
            if (itemBase + 7  < batch) __builtin_nontemporal_store(p1.w, &out[ob + 7  * 256]);
            if (itemBase + 8  < batch) __builtin_nontemporal_store(p2.x, &out[ob + 8  * 256]);
            if (itemBase + 9  < batch) __builtin_nontemporal_store(p2.y, &out[ob + 9  * 256]);
            if (itemBase + 10 < batch) __builtin_nontemporal_store(p2.z, &out[ob + 10 * 256]);
            if (itemBase + 11 < batch) __builtin_nontemporal_store(p2.w, &out[ob + 11 * 256]);
            if (itemBase + 12 < batch) __builtin_nontemporal_store(p3.x, &out[ob + 12 * 256]);
            if (itemBase + 13 < batch) __builtin_nontemporal_store(p3.y, &out[ob + 13 * 256]);
            if (itemBase + 14 < batch) __builtin_nontemporal_store(p3.z, &out[ob + 14 * 256]);
            if (itemBase + 15 < batch) __builtin_nontemporal_store(p3.w, &out[ob + 15 * 256]);
        }
    }
}

extern "C" void kernel_launch(void* const* d_in, const int* in_sizes, int n_in,
                              void* d_out, int out_size, void* d_ws, size_t ws_size,
                              hipStream_t stream) {
    const float* X = (const float*)d_in[0];
    const float* W = (const float*)d_in[1];
    float* out = (float*)d_out;
    const int batch = in_sizes[0] / 784;            // 8192
    const int blocks = (batch + BPB - 1) / BPB;     // 512

    wt_transpose<<<100, 256, 0, stream>>>(W, (float4*)d_ws);
    reservoir_kernel<<<blocks, 256, 0, stream>>>(
        X, (const float4*)d_ws, out, batch);
}